// Round 2
// baseline (2638.231 us; speedup 1.0000x reference)
//
#include <hip/hip_runtime.h>
#include <cmath>

#define NEG -1e9f
constexpr int B = 8, N = 512, M = 512, D = 512;
constexpr size_t NM = (size_t)N * M;

constexpr int SKEW = 64;        // wave time-skew == barrier interval
constexpr int RING = 256;       // ring slots; reuse distance 256 >> lag(65)+interval(64)
constexpr int T_STEPS = 1472;   // 23 chunks of 64 >= (N+M) + 7*SKEW

// ---------------------------------------------------------------------------
// GEMM + activation: which=0 -> theta = softplus(zx . zy^T)
//                    which=1 -> A     = log_sigmoid(gx . gy^T)
// 64x64 tile, 256 threads (16x16), 4x4 microtile, K-tile 16, fp32.
// ---------------------------------------------------------------------------
__global__ __launch_bounds__(256)
void gemm_act_kernel(const float* __restrict__ zx, const float* __restrict__ zy,
                     const float* __restrict__ gx, const float* __restrict__ gy,
                     float* __restrict__ out_theta, float* __restrict__ out_A)
{
    const int bz = blockIdx.z;
    const int b = bz >> 1, which = bz & 1;
    const float* X = (which ? gx : zx) + (size_t)b * N * D;
    const float* Y = (which ? gy : zy) + (size_t)b * M * D;
    float* C = (which ? out_A : out_theta) + (size_t)b * NM;

    __shared__ float Xs[16][68];
    __shared__ float Ys[16][68];

    const int tx = threadIdx.x, ty = threadIdx.y;
    const int t = ty * 16 + tx;
    const int lrow = t >> 2;
    const int lk4 = (t & 3) * 4;
    const int row0 = blockIdx.y * 64, col0 = blockIdx.x * 64;

    float acc[4][4] = {};

    for (int k0 = 0; k0 < D; k0 += 16) {
        const float4 xv = *(const float4*)&X[(row0 + lrow) * D + k0 + lk4];
        const float4 yv = *(const float4*)&Y[(col0 + lrow) * D + k0 + lk4];
        Xs[lk4 + 0][lrow] = xv.x; Xs[lk4 + 1][lrow] = xv.y;
        Xs[lk4 + 2][lrow] = xv.z; Xs[lk4 + 3][lrow] = xv.w;
        Ys[lk4 + 0][lrow] = yv.x; Ys[lk4 + 1][lrow] = yv.y;
        Ys[lk4 + 2][lrow] = yv.z; Ys[lk4 + 3][lrow] = yv.w;
        __syncthreads();
#pragma unroll
        for (int kk = 0; kk < 16; kk++) {
            const float4 a = *(const float4*)&Xs[kk][ty * 4];
            const float4 bb = *(const float4*)&Ys[kk][tx * 4];
            acc[0][0] += a.x * bb.x; acc[0][1] += a.x * bb.y; acc[0][2] += a.x * bb.z; acc[0][3] += a.x * bb.w;
            acc[1][0] += a.y * bb.x; acc[1][1] += a.y * bb.y; acc[1][2] += a.y * bb.z; acc[1][3] += a.y * bb.w;
            acc[2][0] += a.z * bb.x; acc[2][1] += a.z * bb.y; acc[2][2] += a.z * bb.z; acc[2][3] += a.z * bb.w;
            acc[3][0] += a.w * bb.x; acc[3][1] += a.w * bb.y; acc[3][2] += a.w * bb.z; acc[3][3] += a.w * bb.w;
        }
        __syncthreads();
    }

#pragma unroll
    for (int r = 0; r < 4; r++) {
        float4 o;
        float* op = &o.x;
#pragma unroll
        for (int c = 0; c < 4; c++) {
            const float x = acc[r][c];
            const float l = log1pf(expf(-fabsf(x)));
            op[c] = which ? (fminf(x, 0.0f) - l)     // log_sigmoid
                          : (fmaxf(x, 0.0f) + l);   // softplus
        }
        *(float4*)&C[(size_t)(row0 + ty * 4 + r) * M + col0 + tx * 4] = o;
    }
}

// ---------------------------------------------------------------------------
// Forward soft-NW, skewed wave pipeline.
//  lane = row i = 64*w + lane + 1.  Wave w's diagonal at loop time t:
//  k = t + 2 - w*SKEW.  Lane computes cell (i, j=k-i) when 1<=j<=M.
//  Deps: up  = V[i-1][j]   = lane-1's value @ k-1  (shfl_up of vprev)
//        diag= V[i-1][j-1] = lane-1's value @ k-2  (shfl_up of vprev2)
//        left= V[i][j-1]   = own vprev
//  Lane 0 reads wave w-1's bottom row from an LDS ring (lag = SKEW+1 = 65;
//  one __syncthreads per SKEW=64 steps makes the write visible; slot reuse
//  distance RING=256 > lag + interval, so no overwrite race).
// ---------------------------------------------------------------------------
__global__ __launch_bounds__(512)
void nw_forward_kernel(const float* __restrict__ theta, const float* __restrict__ A,
                       float* __restrict__ p_up, float* __restrict__ p_dg,
                       float* __restrict__ p_lf)
{
    const int b = blockIdx.x;
    const int tid = threadIdx.x;
    const int w = tid >> 6;         // wave 0..7
    const int lane = tid & 63;
    const int i = tid + 1;          // 1-based row
    const int r = tid;              // 0-based row

    __shared__ float ring[8][RING];
    for (int x = tid; x < 8 * RING; x += 512) ((float*)ring)[x] = NEG;
    __syncthreads();

    const size_t base = (size_t)b * NM;
    const float* thb = theta + base;
    const float* Ab  = A + base;
    float* pub = p_up + base;
    float* pdb = p_dg + base;
    float* plb = p_lf + base;

    float vprev = NEG, vprev2 = NEG;
    int idx = r * M;                // advances along the lane's row

    for (int t0 = 0; t0 < T_STEPS; t0 += SKEW) {
#pragma unroll 4
        for (int s = 0; s < SKEW; ++s) {
            const int k = t0 + s + 2 - w * SKEW;   // wave-local diagonal
            const int j = k - i;

            float sh1 = __shfl_up(vprev, 1);       // lane-1 @ k-1 -> V[i-1][j]
            float sh2 = __shfl_up(vprev2, 1);      // lane-1 @ k-2 -> V[i-1][j-1]
            if (lane == 0) {
                if (w == 0) { sh1 = NEG; sh2 = NEG; }           // V[0][j>=1] = NEG
                else {
                    sh1 = ring[w - 1][(k - 1) & (RING - 1)];
                    sh2 = ring[w - 1][(k - 2) & (RING - 1)];
                }
            }
            const float diag = (j == 1) ? ((i == 1) ? 0.0f : NEG) : sh2;  // V[i-1][0]

            if (j >= 1 && j <= M) {
                const float th = thb[idx];
                const float a  = Ab[idx];
                const float x0 = a + sh1;      // up
                const float x1 = diag;         // diag
                const float x2 = a + vprev;    // left
                const float m = fmaxf(fmaxf(x0, x1), x2);
                const float e0 = __expf(x0 - m);
                const float e1 = __expf(x1 - m);
                const float e2 = __expf(x2 - m);
                const float sum = e0 + e1 + e2;
                const float inv = 1.0f / sum;
                pub[idx] = e0 * inv;
                pdb[idx] = e1 * inv;
                plb[idx] = e2 * inv;
                const float vnew = th + m + __logf(sum);
                vprev2 = vprev;
                vprev  = vnew;
                if (lane == 63) ring[w][k & (RING - 1)] = vnew;
                idx++;
            }
        }
        __syncthreads();
    }
}

// ---------------------------------------------------------------------------
// Backward adjoint, mirrored pipeline (wave 7 leads, k decreasing):
//  k = (N+M) - t + (7-w)*SKEW.
//  E[i,j] = p_up(i+1,j) E[i+1,j] + p_dg(i+1,j+1) E[i+1,j+1] + p_lf(i,j+1) E[i,j+1]
//  Deps: E[i+1][j]   = lane+1 @ k+1 (shfl_down of eprev)
//        E[i+1][j+1] = lane+1 @ k+2 (shfl_down of eprev2)
//        E[i][j+1]   = own eprev
//  Lane 63 reads wave w+1's top row from the LDS ring.
// ---------------------------------------------------------------------------
__global__ __launch_bounds__(512)
void nw_backward_kernel(const float* __restrict__ p_up, const float* __restrict__ p_dg,
                        const float* __restrict__ p_lf, float* __restrict__ aln)
{
    const int b = blockIdx.x;
    const int tid = threadIdx.x;
    const int w = tid >> 6;
    const int lane = tid & 63;
    const int i = tid + 1;          // 1-based row
    const int r = tid;              // 0-based row

    __shared__ float ring[8][RING];
    for (int x = tid; x < 8 * RING; x += 512) ((float*)ring)[x] = 0.0f;
    __syncthreads();

    const size_t base = (size_t)b * NM;
    const float* pub = p_up + base;
    const float* pdb = p_dg + base;
    const float* plb = p_lf + base;
    float* alb = aln + base;

    float eprev = 0.0f, eprev2 = 0.0f;

    for (int t0 = 0; t0 < T_STEPS; t0 += SKEW) {
#pragma unroll 4
        for (int s = 0; s < SKEW; ++s) {
            const int t = t0 + s;
            const int k = (N + M) - t + (7 - w) * SKEW;  // wave-local diagonal
            const int j = k - i;

            float sh1 = __shfl_down(eprev, 1);    // lane+1 @ k+1 -> E[i+1][j]
            float sh2 = __shfl_down(eprev2, 1);   // lane+1 @ k+2 -> E[i+1][j+1]
            if (lane == 63) {
                if (w == 7) { sh1 = 0.0f; sh2 = 0.0f; }        // E[N+1][*] = 0
                else {
                    sh1 = ring[w + 1][(k + 1) & (RING - 1)];
                    sh2 = ring[w + 1][(k + 2) & (RING - 1)];
                }
            }

            if (j >= 1 && j <= M) {
                float e;
                if (i == N && j == M) {
                    e = 1.0f;
                } else {
                    e = 0.0f;
                    if (i < N)          e += pub[(size_t)i * M + (j - 1)] * sh1;
                    if (i < N && j < M) e += pdb[(size_t)i * M + j]       * sh2;
                    if (j < M)          e += plb[(size_t)r * M + j]       * eprev;
                }
                alb[(size_t)r * M + (j - 1)] = e;
                eprev2 = eprev;
                eprev  = e;
                if (lane == 0) ring[w][k & (RING - 1)] = e;
            }
        }
        __syncthreads();
    }
}

// ---------------------------------------------------------------------------
extern "C" void kernel_launch(void* const* d_in, const int* in_sizes, int n_in,
                              void* d_out, int out_size, void* d_ws, size_t ws_size,
                              hipStream_t stream) {
    const float* zx = (const float*)d_in[0];
    const float* zy = (const float*)d_in[1];
    const float* gx = (const float*)d_in[2];
    const float* gy = (const float*)d_in[3];

    float* aln   = (float*)d_out;               // output 0: [B,N,M]
    float* theta = aln + B * NM;                // output 1
    float* Amat  = theta + B * NM;              // output 2

    float* p_up = (float*)d_ws;                 // 3 x B*N*M fp32 = 25.2 MB scratch
    float* p_dg = p_up + B * NM;
    float* p_lf = p_dg + B * NM;

    dim3 gb(M / 64, N / 64, B * 2);
    gemm_act_kernel<<<gb, dim3(16, 16), 0, stream>>>(zx, zy, gx, gy, theta, Amat);
    nw_forward_kernel<<<B, 512, 0, stream>>>(theta, Amat, p_up, p_dg, p_lf);
    nw_backward_kernel<<<B, 512, 0, stream>>>(p_up, p_dg, p_lf, aln);
}

// Round 3
// 2489.381 us; speedup vs baseline: 1.0598x; 1.0598x over previous
//
#include <hip/hip_runtime.h>
#include <cmath>

#define NEG -1e9f
constexpr int B = 8, N = 512, M = 512, D = 512;
constexpr size_t NM = (size_t)N * M;

constexpr int SKEW = 64;        // wave time-skew (wave w lags w-1 by 64 steps)
constexpr int RING = 128;       // ring slots; reuse distance 128 > lag(65)+prefetch(15)
constexpr int CH = 16;          // chunk = barrier interval = tile width
constexpr int NCH = 92;         // 92*16 = 1472 >= 1023 + 7*64 + 1
constexpr int PADW = 17;        // LDS tile row stride (pad -> <=2-way banks, free)

// ---------------------------------------------------------------------------
// GEMM + activation: which=0 -> theta = softplus(zx . zy^T)
//                    which=1 -> A     = log_sigmoid(gx . gy^T)
// ---------------------------------------------------------------------------
__global__ __launch_bounds__(256)
void gemm_act_kernel(const float* __restrict__ zx, const float* __restrict__ zy,
                     const float* __restrict__ gx, const float* __restrict__ gy,
                     float* __restrict__ out_theta, float* __restrict__ out_A)
{
    const int bz = blockIdx.z;
    const int b = bz >> 1, which = bz & 1;
    const float* X = (which ? gx : zx) + (size_t)b * N * D;
    const float* Y = (which ? gy : zy) + (size_t)b * M * D;
    float* C = (which ? out_A : out_theta) + (size_t)b * NM;

    __shared__ float Xs[16][68];
    __shared__ float Ys[16][68];

    const int tx = threadIdx.x, ty = threadIdx.y;
    const int t = ty * 16 + tx;
    const int lrow = t >> 2;
    const int lk4 = (t & 3) * 4;
    const int row0 = blockIdx.y * 64, col0 = blockIdx.x * 64;

    float acc[4][4] = {};

    for (int k0 = 0; k0 < D; k0 += 16) {
        const float4 xv = *(const float4*)&X[(row0 + lrow) * D + k0 + lk4];
        const float4 yv = *(const float4*)&Y[(col0 + lrow) * D + k0 + lk4];
        Xs[lk4 + 0][lrow] = xv.x; Xs[lk4 + 1][lrow] = xv.y;
        Xs[lk4 + 2][lrow] = xv.z; Xs[lk4 + 3][lrow] = xv.w;
        Ys[lk4 + 0][lrow] = yv.x; Ys[lk4 + 1][lrow] = yv.y;
        Ys[lk4 + 2][lrow] = yv.z; Ys[lk4 + 3][lrow] = yv.w;
        __syncthreads();
#pragma unroll
        for (int kk = 0; kk < 16; kk++) {
            const float4 a = *(const float4*)&Xs[kk][ty * 4];
            const float4 bb = *(const float4*)&Ys[kk][tx * 4];
            acc[0][0] += a.x * bb.x; acc[0][1] += a.x * bb.y; acc[0][2] += a.x * bb.z; acc[0][3] += a.x * bb.w;
            acc[1][0] += a.y * bb.x; acc[1][1] += a.y * bb.y; acc[1][2] += a.y * bb.z; acc[1][3] += a.y * bb.w;
            acc[2][0] += a.z * bb.x; acc[2][1] += a.z * bb.y; acc[2][2] += a.z * bb.z; acc[2][3] += a.z * bb.w;
            acc[3][0] += a.w * bb.x; acc[3][1] += a.w * bb.y; acc[3][2] += a.w * bb.z; acc[3][3] += a.w * bb.w;
        }
        __syncthreads();
    }

#pragma unroll
    for (int r = 0; r < 4; r++) {
        float4 o;
        float* op = &o.x;
#pragma unroll
        for (int c = 0; c < 4; c++) {
            const float x = acc[r][c];
            const float l = log1pf(expf(-fabsf(x)));
            op[c] = which ? (fminf(x, 0.0f) - l)     // log_sigmoid
                          : (fmaxf(x, 0.0f) + l);   // softplus
        }
        *(float4*)&C[(size_t)(row0 + ty * 4 + r) * M + col0 + tx * 4] = o;
    }
}

// ---------------------------------------------------------------------------
// Forward soft-NW, skewed wave pipeline + LDS-staged double-buffered tiles.
//  lane/thread = row r = tid (0-based), i = tid+1. off = 128*w + lane.
//  jj(T) = T - off (0-based col), active when jj in [0,512).
//  Diagonal k = T + 2 - 64w.  up = shfl_up(vprev); diag = previous step's up.
//  Stores p_up, p_lf only (p_dg = 1 - up - lf reconstructed in backward).
// ---------------------------------------------------------------------------
__global__ __launch_bounds__(512)
void nw_forward_kernel(const float* __restrict__ theta, const float* __restrict__ A,
                       float* __restrict__ p_up, float* __restrict__ p_lf)
{
    __shared__ float tT[2][512 * PADW];
    __shared__ float tA[2][512 * PADW];
    __shared__ float ring[8][RING];

    const int b = blockIdx.x;
    const int tid = threadIdx.x;
    const int w = tid >> 6, lane = tid & 63;
    const int off = 128 * w + lane;

    const size_t base = (size_t)b * NM + (size_t)tid * M;
    const float* thb = theta + base;      // own row
    const float* Ab  = A + base;
    float* pub = p_up + base;
    float* plb = p_lf + base;

    for (int x = tid; x < 8 * RING; x += 512) ((float*)ring)[x] = NEG;

    // stage chunk 0 (clamped addresses; out-of-window values guarded at compute)
    {
        const int jlo = -off;
#pragma unroll
        for (int e = 0; e < CH; e++) {
            const int jj = min(max(jlo + e, 0), M - 1);
            tT[0][tid * PADW + e] = thb[jj];
            tA[0][tid * PADW + e] = Ab[jj];
        }
    }
    __syncthreads();

    float vprev = NEG;     // own V from previous valid step (V[i, j-1])
    float sh1_d = NEG;     // previous step's shfl result -> V[i-1, j-1]
    float rT[CH], rA[CH];

    for (int c = 0; c < NCH; c++) {
        const int cb = c & 1;

        if (c + 1 < NCH) {                 // issue next chunk's global loads early
            const int jlo = (c + 1) * CH - off;
#pragma unroll
            for (int e = 0; e < CH; e++) {
                const int jj = min(max(jlo + e, 0), M - 1);
                rT[e] = thb[jj];
                rA[e] = Ab[jj];
            }
        }

        // ring prefetch: lane0 of wave w needs ring[w-1] slot (k-1) = kb+s
        float rg[CH];
        {
            const int kb = 16 * c + 1 - 64 * w;
#pragma unroll
            for (int s = 0; s < CH; s++)
                rg[s] = (w > 0) ? ring[w - 1][(kb + s) & (RING - 1)] : NEG;
        }

        const float* bT = &tT[cb][tid * PADW];
        const float* bA = &tA[cb][tid * PADW];
#pragma unroll
        for (int s = 0; s < CH; s++) {
            const int jj = 16 * c + s - off;
            float sh1 = __shfl_up(vprev, 1);          // all lanes participate
            if (lane == 0) sh1 = rg[s];               // wave-boundary: V[i-1, j]
            const float diag = (jj == 0) ? ((tid == 0) ? 0.0f : NEG) : sh1_d;
            sh1_d = sh1;
            if (jj >= 0 && jj < M) {
                const float th = bT[s];
                const float a  = bA[s];
                const float x0 = a + sh1;             // up
                const float x2 = a + vprev;           // left
                const float m = fmaxf(fmaxf(x0, diag), x2);
                const float e0 = __expf(x0 - m);
                const float e1 = __expf(diag - m);
                const float e2 = __expf(x2 - m);
                const float sum = e0 + e1 + e2;
                const float inv = 1.0f / sum;
                pub[jj] = e0 * inv;
                plb[jj] = e2 * inv;
                vprev = th + m + __logf(sum);
                if (lane == 63)
                    ring[w][(16 * c + s + 2 - 64 * w) & (RING - 1)] = vprev;
            }
        }

        if (c + 1 < NCH) {
#pragma unroll
            for (int e = 0; e < CH; e++) {
                tT[cb ^ 1][tid * PADW + e] = rT[e];
                tA[cb ^ 1][tid * PADW + e] = rA[e];
            }
            __syncthreads();
        }
    }
}

// ---------------------------------------------------------------------------
// Backward adjoint, q-product formulation (all loads at OWN cell index):
//  per valid cell: e = su + sd + ql1;  q_up = p_up*e; q_dg = p_dg*e; q_lf = p_lf*e
//  where su = lane+1's q_up from 1 iter ago, sd = lane+1's q_dg from 2 iters
//  ago, ql1 = own q_lf from 1 iter ago. p_dg = 1 - p_up - p_lf.
//  jj(T) = 1470 - T - off (descending). Diagonal k = 1472 - T - 64w.
//  Wave boundary (lane 63) reads wave w+1's lane-0 q values from rings.
// ---------------------------------------------------------------------------
__global__ __launch_bounds__(512)
void nw_backward_kernel(const float* __restrict__ p_up, const float* __restrict__ p_lf,
                        float* __restrict__ aln)
{
    __shared__ float tU[2][512 * PADW];
    __shared__ float tL[2][512 * PADW];
    __shared__ float ring_u[8][RING];
    __shared__ float ring_d[8][RING];

    const int b = blockIdx.x;
    const int tid = threadIdx.x;
    const int w = tid >> 6, lane = tid & 63;
    const int off = 128 * w + lane;

    const size_t base = (size_t)b * NM + (size_t)tid * M;
    const float* pub = p_up + base;       // own row
    const float* plb = p_lf + base;
    float* alb = aln + base;

    for (int x = tid; x < 8 * RING; x += 512) {
        ((float*)ring_u)[x] = 0.0f;
        ((float*)ring_d)[x] = 0.0f;
    }

    // stage chunk 0: tile x ascending <-> jj = jjlo + x, jjlo = 1470-off-0*16-15
    {
        const int jlo = 1470 - off - 15;
#pragma unroll
        for (int e = 0; e < CH; e++) {
            const int jj = min(max(jlo + e, 0), M - 1);
            tU[0][tid * PADW + e] = pub[jj];
            tL[0][tid * PADW + e] = plb[jj];
        }
    }
    __syncthreads();

    float qu1 = 0.0f;   // own q_up  from 1 iter ago
    float qd1 = 0.0f;   // own q_dg  from 1 iter ago
    float qd2 = 0.0f;   // own q_dg  from 2 iters ago
    float ql1 = 0.0f;   // own q_lf  from 1 iter ago
    float rU[CH], rL[CH];

    for (int c = 0; c < NCH; c++) {
        const int cb = c & 1;

        if (c + 1 < NCH) {
            const int jlo = 1470 - off - (c + 1) * CH - 15;
#pragma unroll
            for (int e = 0; e < CH; e++) {
                const int jj = min(max(jlo + e, 0), M - 1);
                rU[e] = pub[jj];
                rL[e] = plb[jj];
            }
        }

        // ring prefetch: lane63 of wave w needs ring[w+1] slots (k+1),(k+2);
        // k(s) = K0 - s with K0 = 1472 - 64w - 16c
        float rgu[CH], rgd[CH];
        {
            const int K0 = 1472 - 64 * w - 16 * c;
#pragma unroll
            for (int s = 0; s < CH; s++) {
                rgu[s] = (w < 7) ? ring_u[w + 1][(K0 + 1 - s) & (RING - 1)] : 0.0f;
                rgd[s] = (w < 7) ? ring_d[w + 1][(K0 + 2 - s) & (RING - 1)] : 0.0f;
            }
        }

        const float* bU = &tU[cb][tid * PADW];
        const float* bL = &tL[cb][tid * PADW];
        const int K0 = 1472 - 64 * w - 16 * c;
#pragma unroll
        for (int s = 0; s < CH; s++) {
            const int jj = 1470 - off - (16 * c + s);
            float su = __shfl_down(qu1, 1);           // lane+1 q_up @ k+1
            float sd = __shfl_down(qd2, 1);           // lane+1 q_dg @ k+2
            if (lane == 63) { su = rgu[s]; sd = rgd[s]; }
            if (jj >= 0 && jj < M) {
                float e = su + sd + ql1;
                if (tid == 511 && jj == M - 1) e = 1.0f;   // E[N,M] seed
                const float pu = bU[15 - s];
                const float pl = bL[15 - s];
                const float pd = 1.0f - pu - pl;
                const float qu = pu * e;
                const float qd = pd * e;
                const float ql = pl * e;
                alb[jj] = e;
                qd2 = qd1; qd1 = qd; qu1 = qu; ql1 = ql;
                if (lane == 0) {
                    ring_u[w][(K0 - s) & (RING - 1)] = qu;
                    ring_d[w][(K0 - s) & (RING - 1)] = qd;
                }
            }
        }

        if (c + 1 < NCH) {
#pragma unroll
            for (int e = 0; e < CH; e++) {
                tU[cb ^ 1][tid * PADW + e] = rU[e];
                tL[cb ^ 1][tid * PADW + e] = rL[e];
            }
            __syncthreads();
        }
    }
}

// ---------------------------------------------------------------------------
extern "C" void kernel_launch(void* const* d_in, const int* in_sizes, int n_in,
                              void* d_out, int out_size, void* d_ws, size_t ws_size,
                              hipStream_t stream) {
    const float* zx = (const float*)d_in[0];
    const float* zy = (const float*)d_in[1];
    const float* gx = (const float*)d_in[2];
    const float* gy = (const float*)d_in[3];

    float* aln   = (float*)d_out;               // output 0: [B,N,M]
    float* theta = aln + B * NM;                // output 1
    float* Amat  = theta + B * NM;              // output 2

    float* p_up = (float*)d_ws;                 // 2 x B*N*M fp32 = 16.8 MB scratch
    float* p_lf = p_up + B * NM;

    dim3 gb(M / 64, N / 64, B * 2);
    gemm_act_kernel<<<gb, dim3(16, 16), 0, stream>>>(zx, zy, gx, gy, theta, Amat);
    nw_forward_kernel<<<B, 512, 0, stream>>>(theta, Amat, p_up, p_lf);
    nw_backward_kernel<<<B, 512, 0, stream>>>(p_up, p_lf, aln);
}

// Round 4
// 982.103 us; speedup vs baseline: 2.6863x; 2.5347x over previous
//
#include <hip/hip_runtime.h>
#include <cmath>

#define NEG -1e9f
constexpr int B = 8, N = 512, M = 512, D = 512;
constexpr size_t NM = (size_t)N * M;   // 262144

constexpr int RING = 128;       // ring slots; reuse distance 128 > lag(65)+chunk(16)
constexpr int CH = 16;          // chunk = barrier interval
constexpr int NCH = 92;         // 92*16 = 1472 steps >= 1471 needed

// Compact diagonal layout: cell (r,c) 0-based -> off(kd) + r - rmin(kd), kd=r+c.
// diag kd has len = kd+1 (kd<=511) else 1023-kd; total = exactly N*M.
__device__ __forceinline__ int diag_off(int kd) {
    return (kd <= 511) ? ((kd * (kd + 1)) >> 1)
                       : ((int)NM - (((1023 - kd) * (1024 - kd)) >> 1));
}
__device__ __forceinline__ int diag_flat_clamped(int kd, int r) {
    const int k = min(max(kd, 0), 1022);
    const int f = diag_off(k) + r - max(0, k - 511);
    return min(max(f, 0), (int)NM - 1);
}

// ---------------------------------------------------------------------------
// GEMM + activation: which=0 -> theta = softplus(zx . zy^T)
//                    which=1 -> A     = log_sigmoid(gx . gy^T)
// ---------------------------------------------------------------------------
__global__ __launch_bounds__(256)
void gemm_act_kernel(const float* __restrict__ zx, const float* __restrict__ zy,
                     const float* __restrict__ gx, const float* __restrict__ gy,
                     float* __restrict__ out_theta, float* __restrict__ out_A)
{
    const int bz = blockIdx.z;
    const int b = bz >> 1, which = bz & 1;
    const float* X = (which ? gx : zx) + (size_t)b * N * D;
    const float* Y = (which ? gy : zy) + (size_t)b * M * D;
    float* C = (which ? out_A : out_theta) + (size_t)b * NM;

    __shared__ float Xs[16][68];
    __shared__ float Ys[16][68];

    const int tx = threadIdx.x, ty = threadIdx.y;
    const int t = ty * 16 + tx;
    const int lrow = t >> 2;
    const int lk4 = (t & 3) * 4;
    const int row0 = blockIdx.y * 64, col0 = blockIdx.x * 64;

    float acc[4][4] = {};

    for (int k0 = 0; k0 < D; k0 += 16) {
        const float4 xv = *(const float4*)&X[(row0 + lrow) * D + k0 + lk4];
        const float4 yv = *(const float4*)&Y[(col0 + lrow) * D + k0 + lk4];
        Xs[lk4 + 0][lrow] = xv.x; Xs[lk4 + 1][lrow] = xv.y;
        Xs[lk4 + 2][lrow] = xv.z; Xs[lk4 + 3][lrow] = xv.w;
        Ys[lk4 + 0][lrow] = yv.x; Ys[lk4 + 1][lrow] = yv.y;
        Ys[lk4 + 2][lrow] = yv.z; Ys[lk4 + 3][lrow] = yv.w;
        __syncthreads();
#pragma unroll
        for (int kk = 0; kk < 16; kk++) {
            const float4 a = *(const float4*)&Xs[kk][ty * 4];
            const float4 bb = *(const float4*)&Ys[kk][tx * 4];
            acc[0][0] += a.x * bb.x; acc[0][1] += a.x * bb.y; acc[0][2] += a.x * bb.z; acc[0][3] += a.x * bb.w;
            acc[1][0] += a.y * bb.x; acc[1][1] += a.y * bb.y; acc[1][2] += a.y * bb.z; acc[1][3] += a.y * bb.w;
            acc[2][0] += a.z * bb.x; acc[2][1] += a.z * bb.y; acc[2][2] += a.z * bb.z; acc[2][3] += a.z * bb.w;
            acc[3][0] += a.w * bb.x; acc[3][1] += a.w * bb.y; acc[3][2] += a.w * bb.z; acc[3][3] += a.w * bb.w;
        }
        __syncthreads();
    }

#pragma unroll
    for (int r = 0; r < 4; r++) {
        float4 o;
        float* op = &o.x;
#pragma unroll
        for (int c = 0; c < 4; c++) {
            const float x = acc[r][c];
            const float l = log1pf(expf(-fabsf(x)));
            op[c] = which ? (fminf(x, 0.0f) - l)     // log_sigmoid
                          : (fmaxf(x, 0.0f) + l);   // softplus
        }
        *(float4*)&C[(size_t)(row0 + ty * 4 + r) * M + col0 + tx * 4] = o;
    }
}

// ---------------------------------------------------------------------------
// Row-major -> compact-diag reorder for theta and A (both-sides coalesced).
// ---------------------------------------------------------------------------
__global__ __launch_bounds__(256)
void reorder_in_kernel(const float* __restrict__ theta, const float* __restrict__ A,
                       float* __restrict__ thetaD, float* __restrict__ AD)
{
    __shared__ float T[64][67];   // stride 67 -> diag reads are 2-way banks (free)
    const int bz = blockIdx.z;
    const int b = bz >> 1, which = bz & 1;
    const float* src = (which ? A : theta) + (size_t)b * NM;
    float* dst = (which ? AD : thetaD) + (size_t)b * NM;
    const int r0 = blockIdx.y * 64, c0 = blockIdx.x * 64;
    const int t = threadIdx.x, lane = t & 63, wv = t >> 6;

#pragma unroll
    for (int e = 0; e < 16; e++) {
        const int r = wv * 16 + e;
        T[r][lane] = src[(size_t)(r0 + r) * M + c0 + lane];
    }
    __syncthreads();
    for (int dd = wv; dd < 127; dd += 4) {
        const int kd = r0 + c0 + dd;
        const int rlo = max(0, dd - 63);
        const int L = min(63, dd) - rlo + 1;
        if (lane < L) {
            const int rloc = rlo + lane;
            const int gr = r0 + rloc;
            dst[diag_off(kd) + gr - max(0, kd - 511)] = T[rloc][dd - rloc];
        }
    }
}

// ---------------------------------------------------------------------------
// Compact-diag -> row-major reorder for E -> aln.
// ---------------------------------------------------------------------------
__global__ __launch_bounds__(256)
void reorder_out_kernel(const float* __restrict__ ED, float* __restrict__ aln)
{
    __shared__ float T[64][67];
    const int b = blockIdx.z;
    const float* src = ED + (size_t)b * NM;
    float* dst = aln + (size_t)b * NM;
    const int r0 = blockIdx.y * 64, c0 = blockIdx.x * 64;
    const int t = threadIdx.x, lane = t & 63, wv = t >> 6;

    for (int dd = wv; dd < 127; dd += 4) {
        const int kd = r0 + c0 + dd;
        const int rlo = max(0, dd - 63);
        const int L = min(63, dd) - rlo + 1;
        if (lane < L) {
            const int rloc = rlo + lane;
            const int gr = r0 + rloc;
            T[rloc][dd - rloc] = src[diag_off(kd) + gr - max(0, kd - 511)];
        }
    }
    __syncthreads();
#pragma unroll
    for (int e = 0; e < 16; e++) {
        const int r = wv * 16 + e;
        dst[(size_t)(r0 + r) * M + c0 + lane] = T[r][lane];
    }
}

// ---------------------------------------------------------------------------
// Forward soft-NW: skewed wave pipeline, all vmem in compact-diag layout
// (lane-consecutive => coalesced). Register-staged chunks, ring in LDS.
//  Thread = row r = tid. Wave w lags by 64 steps: kd = 16c+s - 64w (0-based diag),
//  cell col jj = kd - tid, valid jj in [0,512).
// ---------------------------------------------------------------------------
__global__ __launch_bounds__(512)
void nw_forward_kernel(const float* __restrict__ thetaD, const float* __restrict__ AD,
                       float* __restrict__ puD, float* __restrict__ plD)
{
    __shared__ float ring[8][RING];

    const int b = blockIdx.x;
    const int tid = threadIdx.x;
    const int w = tid >> 6, lane = tid & 63;
    const size_t base = (size_t)b * NM;
    const float* thb = thetaD + base;
    const float* Ab  = AD + base;
    float* pub = puD + base;
    float* plb = plD + base;

    for (int x = tid; x < 8 * RING; x += 512) ((float*)ring)[x] = NEG;
    __syncthreads();

    float cT[CH], cA[CH], rT[CH], rA[CH];
#pragma unroll
    for (int s = 0; s < CH; s++) {            // stage chunk 0
        const int f = diag_flat_clamped(s - 64 * w, tid);
        cT[s] = thb[f]; cA[s] = Ab[f];
    }

    float vprev = NEG;     // own V at previous step (V[i, j-1])
    float sh1_d = NEG;     // previous step's shfl -> V[i-1, j-1]

    for (int c = 0; c < NCH; c++) {
        if (c + 1 < NCH) {                    // prefetch next chunk into regs
#pragma unroll
            for (int s = 0; s < CH; s++) {
                const int f = diag_flat_clamped(16 * (c + 1) + s - 64 * w, tid);
                rT[s] = thb[f]; rA[s] = Ab[f];
            }
        }
        float rg[CH];                          // ring prefetch (slots >=50 steps old)
        {
            const int kb = 16 * c + 1 - 64 * w;
#pragma unroll
            for (int s = 0; s < CH; s++)
                rg[s] = (w > 0) ? ring[w - 1][(kb + s) & (RING - 1)] : NEG;
        }
#pragma unroll
        for (int s = 0; s < CH; s++) {
            const int kd = 16 * c + s - 64 * w;
            const int jj = kd - tid;
            float sh1 = __shfl_up(vprev, 1);   // V[i-1, j]
            if (lane == 0) sh1 = rg[s];
            const float diag = (jj == 0) ? ((tid == 0) ? 0.0f : NEG) : sh1_d;
            sh1_d = sh1;
            if (jj >= 0 && jj < M) {
                const float th = cT[s], a = cA[s];
                const float x0 = a + sh1;      // up
                const float x2 = a + vprev;    // left
                const float m = fmaxf(fmaxf(x0, diag), x2);
                const float e0 = __expf(x0 - m);
                const float e1 = __expf(diag - m);
                const float e2 = __expf(x2 - m);
                const float sum = e0 + e1 + e2;
                const float inv = 1.0f / sum;
                const int f = diag_off(kd) + tid - max(0, kd - 511);
                pub[f] = e0 * inv;             // coalesced: lanes consecutive
                plb[f] = e2 * inv;
                vprev = th + m + __logf(sum);
                if (lane == 63)
                    ring[w][(kd + 2) & (RING - 1)] = vprev;
            }
        }
        if (c + 1 < NCH) {
#pragma unroll
            for (int s = 0; s < CH; s++) { cT[s] = rT[s]; cA[s] = rA[s]; }
        }
        __syncthreads();                       // ring visibility, 1 per 16 steps
    }
}

// ---------------------------------------------------------------------------
// Backward adjoint, q-product form, compact-diag layout, writes E diag-major.
//  e = su + sd + ql1;  q_* = p_* e;  p_dg = 1 - p_up - p_lf.
//  kd = 1470 - (16c+s) - 64w (descending), jj = kd - tid.
// ---------------------------------------------------------------------------
__global__ __launch_bounds__(512)
void nw_backward_kernel(const float* __restrict__ puD, const float* __restrict__ plD,
                        float* __restrict__ ED)
{
    __shared__ float ring_u[8][RING];
    __shared__ float ring_d[8][RING];

    const int b = blockIdx.x;
    const int tid = threadIdx.x;
    const int w = tid >> 6, lane = tid & 63;
    const size_t base = (size_t)b * NM;
    const float* pub = puD + base;
    const float* plb = plD + base;
    float* eb = ED + base;

    for (int x = tid; x < 8 * RING; x += 512) {
        ((float*)ring_u)[x] = 0.0f;
        ((float*)ring_d)[x] = 0.0f;
    }
    __syncthreads();

    float cU[CH], cL[CH], rU[CH], rL[CH];
#pragma unroll
    for (int s = 0; s < CH; s++) {            // stage chunk 0
        const int f = diag_flat_clamped(1470 - s - 64 * w, tid);
        cU[s] = pub[f]; cL[s] = plb[f];
    }

    float qu1 = 0.0f, qd1 = 0.0f, qd2 = 0.0f, ql1 = 0.0f;

    for (int c = 0; c < NCH; c++) {
        if (c + 1 < NCH) {
#pragma unroll
            for (int s = 0; s < CH; s++) {
                const int f = diag_flat_clamped(1470 - (16 * (c + 1) + s) - 64 * w, tid);
                rU[s] = pub[f]; rL[s] = plb[f];
            }
        }
        const int K0 = 1472 - 64 * w - 16 * c;
        float rgu[CH], rgd[CH];
        {
#pragma unroll
            for (int s = 0; s < CH; s++) {
                rgu[s] = (w < 7) ? ring_u[w + 1][(K0 + 1 - s) & (RING - 1)] : 0.0f;
                rgd[s] = (w < 7) ? ring_d[w + 1][(K0 + 2 - s) & (RING - 1)] : 0.0f;
            }
        }
#pragma unroll
        for (int s = 0; s < CH; s++) {
            const int kd = 1470 - (16 * c + s) - 64 * w;
            const int jj = kd - tid;
            float su = __shfl_down(qu1, 1);    // lane+1 q_up @ k+1
            float sd = __shfl_down(qd2, 1);    // lane+1 q_dg @ k+2
            if (lane == 63) { su = rgu[s]; sd = rgd[s]; }
            if (jj >= 0 && jj < M) {
                float e = su + sd + ql1;
                if (tid == 511 && jj == M - 1) e = 1.0f;   // E[N,M] seed
                const float pu = cU[s], pl = cL[s];
                const float pd = 1.0f - pu - pl;
                const float qu = pu * e, qd = pd * e, ql = pl * e;
                const int f = diag_off(kd) + tid - max(0, kd - 511);
                eb[f] = e;                      // coalesced
                qd2 = qd1; qd1 = qd; qu1 = qu; ql1 = ql;
                if (lane == 0) {
                    ring_u[w][(K0 - s) & (RING - 1)] = qu;
                    ring_d[w][(K0 - s) & (RING - 1)] = qd;
                }
            }
        }
        if (c + 1 < NCH) {
#pragma unroll
            for (int s = 0; s < CH; s++) { cU[s] = rU[s]; cL[s] = rL[s]; }
        }
        __syncthreads();
    }
}

// ---------------------------------------------------------------------------
extern "C" void kernel_launch(void* const* d_in, const int* in_sizes, int n_in,
                              void* d_out, int out_size, void* d_ws, size_t ws_size,
                              hipStream_t stream) {
    const float* zx = (const float*)d_in[0];
    const float* zy = (const float*)d_in[1];
    const float* gx = (const float*)d_in[2];
    const float* gy = (const float*)d_in[3];

    float* aln   = (float*)d_out;               // output 0: [B,N,M]
    float* theta = aln + B * NM;                // output 1
    float* Amat  = theta + B * NM;              // output 2

    float* thetaD = (float*)d_ws;               // 8 MB each; total ws use 32 MB
    float* AD     = thetaD + B * NM;
    float* puD    = AD + B * NM;
    float* plD    = puD + B * NM;
    float* ED     = thetaD;                     // reuse (theta dead after forward)

    gemm_act_kernel<<<dim3(8, 8, B * 2), dim3(16, 16), 0, stream>>>(zx, zy, gx, gy, theta, Amat);
    reorder_in_kernel<<<dim3(8, 8, B * 2), 256, 0, stream>>>(theta, Amat, thetaD, AD);
    nw_forward_kernel<<<B, 512, 0, stream>>>(thetaD, AD, puD, plD);
    nw_backward_kernel<<<B, 512, 0, stream>>>(puD, plD, ED);
    reorder_out_kernel<<<dim3(8, 8, B), 256, 0, stream>>>(ED, aln);
}

// Round 5
// 816.846 us; speedup vs baseline: 3.2298x; 1.2023x over previous
//
#include <hip/hip_runtime.h>
#include <cmath>

#define NEG -1e9f
constexpr int B = 8, N = 512, M = 512, D = 512;
constexpr size_t NM = (size_t)N * M;   // 262144

constexpr int CH = 16;          // chunk = barrier interval = wave skew
constexpr int NCH = 71;         // 71*16 = 1136 >= 1023 + 7*16 + 1 makespan
// Active chunk windows: forward wave w: [5w, 5w+35]; backward: [35-5w, 70-5w].

// Compact diagonal layout: cell (r,c) 0-based -> diag_off(kd) + r - max(0,kd-511)
__device__ __forceinline__ int diag_off(int kd) {
    return (kd <= 511) ? ((kd * (kd + 1)) >> 1)
                       : ((int)NM - (((1023 - kd) * (1024 - kd)) >> 1));
}
__device__ __forceinline__ int diag_flat_clamped(int kd, int r) {
    const int k = min(max(kd, 0), 1022);
    const int f = diag_off(k) + r - max(0, k - 511);
    return min(max(f, 0), (int)NM - 1);
}

// ---------------------------------------------------------------------------
// GEMM + activation: which=0 -> theta = softplus(zx . zy^T)
//                    which=1 -> A     = log_sigmoid(gx . gy^T)
// ---------------------------------------------------------------------------
__global__ __launch_bounds__(256)
void gemm_act_kernel(const float* __restrict__ zx, const float* __restrict__ zy,
                     const float* __restrict__ gx, const float* __restrict__ gy,
                     float* __restrict__ out_theta, float* __restrict__ out_A)
{
    const int bz = blockIdx.z;
    const int b = bz >> 1, which = bz & 1;
    const float* X = (which ? gx : zx) + (size_t)b * N * D;
    const float* Y = (which ? gy : zy) + (size_t)b * M * D;
    float* C = (which ? out_A : out_theta) + (size_t)b * NM;

    __shared__ float Xs[16][68];
    __shared__ float Ys[16][68];

    const int tx = threadIdx.x, ty = threadIdx.y;
    const int t = ty * 16 + tx;
    const int lrow = t >> 2;
    const int lk4 = (t & 3) * 4;
    const int row0 = blockIdx.y * 64, col0 = blockIdx.x * 64;

    float acc[4][4] = {};

    for (int k0 = 0; k0 < D; k0 += 16) {
        const float4 xv = *(const float4*)&X[(row0 + lrow) * D + k0 + lk4];
        const float4 yv = *(const float4*)&Y[(col0 + lrow) * D + k0 + lk4];
        Xs[lk4 + 0][lrow] = xv.x; Xs[lk4 + 1][lrow] = xv.y;
        Xs[lk4 + 2][lrow] = xv.z; Xs[lk4 + 3][lrow] = xv.w;
        Ys[lk4 + 0][lrow] = yv.x; Ys[lk4 + 1][lrow] = yv.y;
        Ys[lk4 + 2][lrow] = yv.z; Ys[lk4 + 3][lrow] = yv.w;
        __syncthreads();
#pragma unroll
        for (int kk = 0; kk < 16; kk++) {
            const float4 a = *(const float4*)&Xs[kk][ty * 4];
            const float4 bb = *(const float4*)&Ys[kk][tx * 4];
            acc[0][0] += a.x * bb.x; acc[0][1] += a.x * bb.y; acc[0][2] += a.x * bb.z; acc[0][3] += a.x * bb.w;
            acc[1][0] += a.y * bb.x; acc[1][1] += a.y * bb.y; acc[1][2] += a.y * bb.z; acc[1][3] += a.y * bb.w;
            acc[2][0] += a.z * bb.x; acc[2][1] += a.z * bb.y; acc[2][2] += a.z * bb.z; acc[2][3] += a.z * bb.w;
            acc[3][0] += a.w * bb.x; acc[3][1] += a.w * bb.y; acc[3][2] += a.w * bb.z; acc[3][3] += a.w * bb.w;
        }
        __syncthreads();
    }

#pragma unroll
    for (int r = 0; r < 4; r++) {
        float4 o;
        float* op = &o.x;
#pragma unroll
        for (int c = 0; c < 4; c++) {
            const float x = acc[r][c];
            const float l = log1pf(expf(-fabsf(x)));
            op[c] = which ? (fminf(x, 0.0f) - l)     // log_sigmoid
                          : (fmaxf(x, 0.0f) + l);   // softplus
        }
        *(float4*)&C[(size_t)(row0 + ty * 4 + r) * M + col0 + tx * 4] = o;
    }
}

// ---------------------------------------------------------------------------
// Row-major theta,A -> compact-diag interleaved float2 {theta, A}.
// ---------------------------------------------------------------------------
__global__ __launch_bounds__(256)
void reorder_in_kernel(const float* __restrict__ theta, const float* __restrict__ A,
                       float2* __restrict__ TAD)
{
    __shared__ float T[64][67];    // stride 67 -> diag reads 2-way banks (free)
    __shared__ float Ag[64][67];
    const int b = blockIdx.z;
    const float* ts = theta + (size_t)b * NM;
    const float* as = A + (size_t)b * NM;
    float2* dst = TAD + (size_t)b * NM;
    const int r0 = blockIdx.y * 64, c0 = blockIdx.x * 64;
    const int t = threadIdx.x, lane = t & 63, wv = t >> 6;

#pragma unroll
    for (int e = 0; e < 16; e++) {
        const int r = wv * 16 + e;
        T[r][lane]  = ts[(size_t)(r0 + r) * M + c0 + lane];
        Ag[r][lane] = as[(size_t)(r0 + r) * M + c0 + lane];
    }
    __syncthreads();
    for (int dd = wv; dd < 127; dd += 4) {
        const int kd = r0 + c0 + dd;
        const int rlo = max(0, dd - 63);
        const int L = min(63, dd) - rlo + 1;
        if (lane < L) {
            const int rloc = rlo + lane;
            const int gr = r0 + rloc;
            dst[diag_off(kd) + gr - max(0, kd - 511)] =
                make_float2(T[rloc][dd - rloc], Ag[rloc][dd - rloc]);
        }
    }
}

// ---------------------------------------------------------------------------
// Compact-diag E -> row-major aln.
// ---------------------------------------------------------------------------
__global__ __launch_bounds__(256)
void reorder_out_kernel(const float* __restrict__ ED, float* __restrict__ aln)
{
    __shared__ float T[64][67];
    const int b = blockIdx.z;
    const float* src = ED + (size_t)b * NM;
    float* dst = aln + (size_t)b * NM;
    const int r0 = blockIdx.y * 64, c0 = blockIdx.x * 64;
    const int t = threadIdx.x, lane = t & 63, wv = t >> 6;

    for (int dd = wv; dd < 127; dd += 4) {
        const int kd = r0 + c0 + dd;
        const int rlo = max(0, dd - 63);
        const int L = min(63, dd) - rlo + 1;
        if (lane < L) {
            const int rloc = rlo + lane;
            const int gr = r0 + rloc;
            T[rloc][dd - rloc] = src[diag_off(kd) + gr - max(0, kd - 511)];
        }
    }
    __syncthreads();
#pragma unroll
    for (int e = 0; e < 16; e++) {
        const int r = wv * 16 + e;
        dst[(size_t)(r0 + r) * M + c0 + lane] = T[r][lane];
    }
}

// ---------------------------------------------------------------------------
// Forward soft-NW: skew=16 wave pipeline, chunk-skipping, float2 staged loads,
// float2 p-store. Thread = row r = tid; wave w computes diag kd at global
// step t = kd + 16w. Ring slot = kd & 63 (written by lane63 at its kd; read
// by wave w+1 lane0 for kd_c-1, 17 steps later -> always a barrier between).
// ---------------------------------------------------------------------------
__global__ __launch_bounds__(512)
void nw_forward_kernel(const float2* __restrict__ TAD, float2* __restrict__ pD)
{
    __shared__ float ring[8][64];
    const int b = blockIdx.x;
    const int tid = threadIdx.x;
    const int w = __builtin_amdgcn_readfirstlane(tid >> 6);
    const int lane = tid & 63;
    const float2* tab = TAD + (size_t)b * NM;
    float2* pb = pD + (size_t)b * NM;

    for (int x = tid; x < 8 * 64; x += 512) ((float*)ring)[x] = NEG;
    __syncthreads();

    const int ca = 5 * w, cb = 5 * w + 35;

    float2 cur[CH], nxt[CH];
    if (w == 0) {
#pragma unroll
        for (int s = 0; s < CH; s++)
            cur[s] = tab[diag_flat_clamped(s, tid)];
    }

    float vprev = NEG, sh1_d = NEG;

    for (int c = 0; c < NCH; c++) {
        const bool pf = (c + 1 >= ca) && (c + 1 <= cb);
        if (pf) {
            const int kb = 16 * (c + 1) - 16 * w;
#pragma unroll
            for (int s = 0; s < CH; s++)
                nxt[s] = tab[diag_flat_clamped(kb + s, tid)];
        }
        if (c >= ca && c <= cb) {
            const int kb = 16 * c - 16 * w;
            float rg[CH];
#pragma unroll
            for (int s = 0; s < CH; s++)
                rg[s] = (w > 0) ? ring[w - 1][(kb + s - 1) & 63] : NEG;
#pragma unroll
            for (int s = 0; s < CH; s++) {
                const int kd = kb + s;
                const int jj = kd - tid;
                float sh1 = __shfl_up(vprev, 1);       // V[i-1, j]
                if (lane == 0) sh1 = rg[s];
                const float dg = (jj == 0) ? ((tid == 0) ? 0.0f : NEG) : sh1_d;
                sh1_d = sh1;
                if (jj >= 0 && jj < M) {
                    const float th = cur[s].x, a = cur[s].y;
                    const float x0 = a + sh1;          // up
                    const float x2 = a + vprev;        // left
                    const float m = fmaxf(fmaxf(x0, dg), x2);
                    const float e0 = __expf(x0 - m);
                    const float e1 = __expf(dg - m);
                    const float e2 = __expf(x2 - m);
                    const float sum = e0 + e1 + e2;
                    const float inv = __builtin_amdgcn_rcpf(sum);
                    const int f = diag_off(kd) + tid - max(0, kd - 511);
                    pb[f] = make_float2(e0 * inv, e2 * inv);   // {p_up, p_lf}
                    vprev = th + m + __logf(sum);
                    if (lane == 63) ring[w][kd & 63] = vprev;
                }
            }
        }
        if (pf) {
#pragma unroll
            for (int s = 0; s < CH; s++) cur[s] = nxt[s];
        }
        __syncthreads();
    }
}

// ---------------------------------------------------------------------------
// Backward adjoint, q-product form, skew=16 mirrored (wave 7 leads):
//  kd = 1134 - t - 16w (descending), jj = kd - tid.
//  e = su + sd + ql1; q_* = p_* e; p_dg = 1 - p_up - p_lf.
//  su = lane+1 q_up @ kd+1 (1 step ago), sd = lane+1 q_dg @ kd+2 (2 ago).
//  Lane 63 reads wave w+1 lane-0 q values from rings (17/18 steps stale).
// ---------------------------------------------------------------------------
__global__ __launch_bounds__(512)
void nw_backward_kernel(const float2* __restrict__ pD, float* __restrict__ ED)
{
    __shared__ float ring_u[8][64];
    __shared__ float ring_d[8][64];
    const int b = blockIdx.x;
    const int tid = threadIdx.x;
    const int w = __builtin_amdgcn_readfirstlane(tid >> 6);
    const int lane = tid & 63;
    const float2* pb = pD + (size_t)b * NM;
    float* eb = ED + (size_t)b * NM;

    for (int x = tid; x < 8 * 64; x += 512) {
        ((float*)ring_u)[x] = 0.0f;
        ((float*)ring_d)[x] = 0.0f;
    }
    __syncthreads();

    const int ca = 35 - 5 * w, cb = 70 - 5 * w;

    float2 cur[CH], nxt[CH];
    if (w == 7) {
#pragma unroll
        for (int s = 0; s < CH; s++)
            cur[s] = pb[diag_flat_clamped(1022 - s, tid)];
    }

    float qu1 = 0.0f, qd1 = 0.0f, qd2 = 0.0f, ql1 = 0.0f;

    for (int c = 0; c < NCH; c++) {
        const bool pf = (c + 1 >= ca) && (c + 1 <= cb);
        if (pf) {
            const int kb = 1134 - 16 * (c + 1) - 16 * w;
#pragma unroll
            for (int s = 0; s < CH; s++)
                nxt[s] = pb[diag_flat_clamped(kb - s, tid)];
        }
        if (c >= ca && c <= cb) {
            const int kb = 1134 - 16 * c - 16 * w;
            float rgu[CH], rgd[CH];
#pragma unroll
            for (int s = 0; s < CH; s++) {
                rgu[s] = (w < 7) ? ring_u[w + 1][(kb - s + 1) & 63] : 0.0f;
                rgd[s] = (w < 7) ? ring_d[w + 1][(kb - s + 2) & 63] : 0.0f;
            }
#pragma unroll
            for (int s = 0; s < CH; s++) {
                const int kd = kb - s;
                const int jj = kd - tid;
                float su = __shfl_down(qu1, 1);    // lane+1 q_up @ kd+1
                float sd = __shfl_down(qd2, 1);    // lane+1 q_dg @ kd+2
                if (lane == 63) { su = rgu[s]; sd = rgd[s]; }
                if (jj >= 0 && jj < M) {
                    float e = su + sd + ql1;
                    if (tid == N - 1 && jj == M - 1) e = 1.0f;   // seed E[N,M]
                    const float pu = cur[s].x, pl = cur[s].y;
                    const float pd = 1.0f - pu - pl;
                    const float qu = pu * e, qd = pd * e, ql = pl * e;
                    const int f = diag_off(kd) + tid - max(0, kd - 511);
                    eb[f] = e;
                    qd2 = qd1; qd1 = qd; qu1 = qu; ql1 = ql;
                    if (lane == 0) {
                        ring_u[w][kd & 63] = qu;
                        ring_d[w][kd & 63] = qd;
                    }
                }
            }
        }
        if (pf) {
#pragma unroll
            for (int s = 0; s < CH; s++) cur[s] = nxt[s];
        }
        __syncthreads();
    }
}

// ---------------------------------------------------------------------------
extern "C" void kernel_launch(void* const* d_in, const int* in_sizes, int n_in,
                              void* d_out, int out_size, void* d_ws, size_t ws_size,
                              hipStream_t stream) {
    const float* zx = (const float*)d_in[0];
    const float* zy = (const float*)d_in[1];
    const float* gx = (const float*)d_in[2];
    const float* gy = (const float*)d_in[3];

    float* aln   = (float*)d_out;               // output 0: [B,N,M]
    float* theta = aln + B * NM;                // output 1
    float* Amat  = theta + B * NM;              // output 2

    float2* TAD = (float2*)d_ws;                // {theta,A} diag-interleaved, 16 MB
    float2* pD  = TAD + B * NM;                 // {p_up,p_lf} diag-interleaved, 16 MB
    float*  ED  = (float*)d_ws;                 // overlays TAD (dead after forward)

    gemm_act_kernel<<<dim3(8, 8, B * 2), dim3(16, 16), 0, stream>>>(zx, zy, gx, gy, theta, Amat);
    reorder_in_kernel<<<dim3(8, 8, B), 256, 0, stream>>>(theta, Amat, TAD);
    nw_forward_kernel<<<B, 512, 0, stream>>>(TAD, pD);
    nw_backward_kernel<<<B, 512, 0, stream>>>(pD, ED);
    reorder_out_kernel<<<dim3(8, 8, B), 256, 0, stream>>>(ED, aln);
}